// Round 1
// baseline (1280.946 us; speedup 1.0000x reference)
//
#include <hip/hip_runtime.h>
#include <cstdint>

// FNet block on MI355X.
//   attn = Re(FFT2(x)) done as bf16 MFMA matmuls:
//     GEMM1: T = X @ [C_D | S_D]          (M=32768, N=1536, K=768)
//     GEMM2: y1 = [C_S | -S_S] @ [Tc;Ts] + x   (per batch, M=4096, N=768, K=8192)
//   LN1 -> out1 (bf16)
//   GEMM3: H = gelu(out1 @ W1 + b1)       (M=32768, N=3072, K=768)
//   GEMM4: y2 = H @ W2 + b2 + out1        (M=32768, N=768, K=3072)
//   LN2 in-place on d_out.
// Workspace requirement: ~267 MiB (H aliases dead FFT buffers). d_out is used
// as fp32 scratch for y1 and y2 (each fully overwritten every call).

typedef __attribute__((ext_vector_type(8))) short short8;
typedef __attribute__((ext_vector_type(4))) float f32x4;

__device__ __forceinline__ unsigned short f2b(float f) {
  union { float f; uint32_t u; } c; c.f = f;
  uint32_t u = c.u;
  u += 0x7FFFu + ((u >> 16) & 1u);   // round-to-nearest-even
  return (unsigned short)(u >> 16);
}
__device__ __forceinline__ float b2f(unsigned short h) {
  union { uint32_t u; float f; } c; c.u = ((uint32_t)h) << 16;
  return c.f;
}

// ---------------------------------------------------------------------------
// Fill / convert kernels
// ---------------------------------------------------------------------------

__global__ __launch_bounds__(256) void f32_to_bf16_vec(
    const float* __restrict__ in, unsigned short* __restrict__ out) {
  long i = (long)blockIdx.x * 256 + threadIdx.x;   // element-of-4 index
  float4 v = reinterpret_cast<const float4*>(in)[i];
  ushort4 o;
  o.x = f2b(v.x); o.y = f2b(v.y); o.z = f2b(v.z); o.w = f2b(v.w);
  reinterpret_cast<ushort4*>(out)[i] = o;
}

// Bt1: (1536 x 768), row j<768: cos(2*pi*j*n/768); row j>=768: sin(2*pi*(j-768)*n/768)
__global__ __launch_bounds__(256) void fill_bt1(unsigned short* __restrict__ Bt1) {
  int i = blockIdx.x * 256 + threadIdx.x;          // < 1536*768
  int j = i / 768;
  int n = i - j * 768;
  int jj = (j >= 768) ? (j - 768) : j;
  int m = (jj * n) % 768;
  float ang = (float)m * (6.283185307179586f / 768.0f);
  float v = (j < 768) ? cosf(ang) : sinf(ang);
  Bt1[i] = f2b(v);
}

// A2: (4096 x 8192), col n1<4096: cos(2*pi*k1*n1/4096); col n1>=4096: -sin(2*pi*k1*(n1-4096)/4096)
__global__ __launch_bounds__(256) void fill_a2(unsigned short* __restrict__ A2) {
  long i = (long)blockIdx.x * 256 + threadIdx.x;   // < 4096*8192
  int k1 = (int)(i >> 13);
  int n1 = (int)(i & 8191);
  int nn = n1 & 4095;
  int mm = (k1 * nn) & 4095;
  float ang = (float)mm * (6.283185307179586f / 4096.0f);
  float v = (n1 < 4096) ? cosf(ang) : -sinf(ang);
  A2[i] = f2b(v);
}

// out[c][r] = bf16(in[r][c]); R,C multiples of 32
__global__ __launch_bounds__(256) void transpose_f32_to_bf16(
    const float* __restrict__ in, unsigned short* __restrict__ out, int R, int C) {
  __shared__ float tile[32][33];
  const int c0 = blockIdx.x * 32;
  const int r0 = blockIdx.y * 32;
  const int tx = threadIdx.x & 31;
  const int ty = threadIdx.x >> 5;   // 0..7
#pragma unroll
  for (int i = ty; i < 32; i += 8)
    tile[i][tx] = in[(long)(r0 + i) * C + c0 + tx];
  __syncthreads();
#pragma unroll
  for (int i = ty; i < 32; i += 8)
    out[(long)(c0 + i) * R + r0 + tx] = f2b(tile[tx][i]);
}

// ---------------------------------------------------------------------------
// GEMM: C = A (MxK, row-major bf16) @ Bt^T (Bt is NxK row-major bf16)
// 128x128 tile, BK=32, 4 waves (2x2), 4x4 fragments of 16x16x32 MFMA.
// Epilogues: 0 = FFT transpose-pack write (GEMM1)
//            1 = +x residual, fp32 out (GEMM2)
//            2 = +bias, exact gelu, bf16 out (GEMM3)
//            3 = +bias +bf16 residual, fp32 out (GEMM4)
// All of M,N multiples of 128 and K multiples of 32 (no bounds checks).
// ---------------------------------------------------------------------------

#define TILE 128
#define BKK 32

template <int EPI>
__global__ __launch_bounds__(256, 2) void gemm_bt(
    const unsigned short* __restrict__ A, const unsigned short* __restrict__ Bt,
    int K, int lda, int ldb, long bBatch,
    float* __restrict__ outF, unsigned short* __restrict__ outB,
    const float* __restrict__ resid, const float* __restrict__ bias,
    const unsigned short* __restrict__ residB, int ldOut) {
  __shared__ __align__(16) unsigned short As[TILE * BKK];
  __shared__ __align__(16) unsigned short Bs[TILE * BKK];
  const int tid = threadIdx.x;
  const int lane = tid & 63;
  const int wave = tid >> 6;
  const int wr = wave >> 1;        // wave row (0..1)
  const int wc = wave & 1;         // wave col (0..1)
  const int z = blockIdx.z;

  const unsigned short* Ab = A + (long)blockIdx.x * TILE * lda;
  const unsigned short* Bb = Bt + (long)z * bBatch + (long)blockIdx.y * TILE * ldb;

  const int srow = lane >> 2;            // 0..15
  const int scol = (lane & 3) << 3;      // 0,8,16,24

  f32x4 acc[4][4] = {};

  for (int k0 = 0; k0 < K; k0 += BKK) {
#pragma unroll
    for (int i = 0; i < 2; ++i) {
      const int chunk = wave * 2 + i;          // 0..7, wave-uniform
      const int row = chunk * 16 + srow;       // tile row this lane stages
      __builtin_amdgcn_global_load_lds(
          (const __attribute__((address_space(1))) void*)(Ab + (long)row * lda + k0 + scol),
          (__attribute__((address_space(3))) void*)(As + chunk * 512), 16, 0, 0);
      __builtin_amdgcn_global_load_lds(
          (const __attribute__((address_space(1))) void*)(Bb + (long)row * ldb + k0 + scol),
          (__attribute__((address_space(3))) void*)(Bs + chunk * 512), 16, 0, 0);
    }
    __syncthreads();   // drains vmcnt (global_load_lds) + lgkm

    short8 af[4], bfr[4];
#pragma unroll
    for (int m = 0; m < 4; ++m)
      af[m] = *reinterpret_cast<const short8*>(
          As + (wr * 64 + m * 16 + (lane & 15)) * BKK + ((lane >> 4) << 3));
#pragma unroll
    for (int n = 0; n < 4; ++n)
      bfr[n] = *reinterpret_cast<const short8*>(
          Bs + (wc * 64 + n * 16 + (lane & 15)) * BKK + ((lane >> 4) << 3));
#pragma unroll
    for (int m = 0; m < 4; ++m)
#pragma unroll
      for (int n = 0; n < 4; ++n)
        acc[m][n] = __builtin_amdgcn_mfma_f32_16x16x32_bf16(af[m], bfr[n], acc[m][n], 0, 0, 0);
    __syncthreads();
  }

  // Epilogue. C/D layout: col = lane&15, row = (lane>>4)*4 + reg  [m89/m91]
  const long rowBase = (long)blockIdx.x * TILE + wr * 64 + ((lane >> 4) << 2);
  const int colBase = blockIdx.y * TILE + wc * 64 + (lane & 15);
#pragma unroll
  for (int m = 0; m < 4; ++m) {
#pragma unroll
    for (int n = 0; n < 4; ++n) {
      const int col = colBase + n * 16;
#pragma unroll
      for (int i = 0; i < 4; ++i) {
        const long r = rowBase + m * 16 + i;
        float v = acc[m][n][i];
        if constexpr (EPI == 0) {
          // T[r][col] -> Bt2[b][d][half*4096 + s]; b=r>>12, s=r&4095
          const long b = r >> 12;
          const long s = r & 4095;
          const long half = (col >= 768) ? 1 : 0;
          const long d = col - half * 768;
          outB[(((b * 768 + d) << 13) | (half << 12) | s)] = f2b(v);
        } else if constexpr (EPI == 1) {
          const long idx = ((long)z * 4096 + r) * 768 + col;
          outF[idx] = v + resid[idx];
        } else if constexpr (EPI == 2) {
          float t = v + bias[col];
          float g = 0.5f * t * (1.0f + erff(t * 0.7071067811865476f));
          outB[r * (long)ldOut + col] = f2b(g);
        } else {
          const long idx = r * 768 + col;
          float t = v + bias[col] + b2f(residB[idx]);
          outF[idx] = t;
        }
      }
    }
  }
}

// ---------------------------------------------------------------------------
// Row LayerNorm over D=768. One 256-thread block per row, 3 elems/thread.
// MODE 0: write bf16 (out1). MODE 1: write fp32 (in-place final output).
// ---------------------------------------------------------------------------
template <int MODE>
__global__ __launch_bounds__(256) void ln_row(
    const float* __restrict__ in, const float* __restrict__ gamma,
    const float* __restrict__ beta, unsigned short* __restrict__ outB,
    float* __restrict__ outF) {
  const long row = blockIdx.x;
  const float* p = in + row * 768;
  const int t = threadIdx.x;
  const float v0 = p[t], v1 = p[t + 256], v2 = p[t + 512];
  float s = v0 + v1 + v2;
  float q = v0 * v0 + v1 * v1 + v2 * v2;
#pragma unroll
  for (int off = 32; off > 0; off >>= 1) {
    s += __shfl_down(s, off, 64);
    q += __shfl_down(q, off, 64);
  }
  __shared__ float ss[4], sq[4];
  if ((t & 63) == 0) { ss[t >> 6] = s; sq[t >> 6] = q; }
  __syncthreads();
  const float S = ss[0] + ss[1] + ss[2] + ss[3];
  const float Q = sq[0] + sq[1] + sq[2] + sq[3];
  const float mu = S * (1.0f / 768.0f);
  const float var = Q * (1.0f / 768.0f) - mu * mu;
  const float rs = rsqrtf(var + 1e-6f);
  const float o0 = (v0 - mu) * rs * gamma[t] + beta[t];
  const float o1 = (v1 - mu) * rs * gamma[t + 256] + beta[t + 256];
  const float o2 = (v2 - mu) * rs * gamma[t + 512] + beta[t + 512];
  if constexpr (MODE == 0) {
    outB[row * 768 + t] = f2b(o0);
    outB[row * 768 + t + 256] = f2b(o1);
    outB[row * 768 + t + 512] = f2b(o2);
  } else {
    outF[row * 768 + t] = o0;
    outF[row * 768 + t + 256] = o1;
    outF[row * 768 + t + 512] = o2;
  }
}

// ---------------------------------------------------------------------------

extern "C" void kernel_launch(void* const* d_in, const int* in_sizes, int n_in,
                              void* d_out, int out_size, void* d_ws, size_t ws_size,
                              hipStream_t stream) {
  const float* x   = (const float*)d_in[0];   // (8,4096,768)
  const float* W1  = (const float*)d_in[1];   // (768,3072)
  const float* b1  = (const float*)d_in[2];   // (3072)
  const float* W2  = (const float*)d_in[3];   // (3072,768)
  const float* b2  = (const float*)d_in[4];   // (768)
  const float* g1  = (const float*)d_in[5];
  const float* be1 = (const float*)d_in[6];
  const float* g2  = (const float*)d_in[7];
  const float* be2 = (const float*)d_in[8];
  float* out = (float*)d_out;                 // fp32, also y1/y2 scratch

  char* ws = (char*)d_ws;
  unsigned short* xb  = (unsigned short*)(ws + 0L);            // 50,331,648
  unsigned short* Bt1 = (unsigned short*)(ws + 50331648L);     //  2,359,296
  unsigned short* A2  = (unsigned short*)(ws + 52690944L);     // 67,108,864
  unsigned short* Bt2 = (unsigned short*)(ws + 119799808L);    // 100,663,296
  unsigned short* H   = (unsigned short*)(ws + 0L);            // 201,326,592 (aliases xb..Bt2, dead by then)
  unsigned short* o1b = (unsigned short*)(ws + 220463104L);    // 50,331,648
  unsigned short* W1t = (unsigned short*)(ws + 270794752L);    //  4,718,592
  unsigned short* W2t = (unsigned short*)(ws + 275513344L);    //  4,718,592
  // total ws needed: 280,231,936 bytes (~267 MiB)

  // --- prep ---
  f32_to_bf16_vec<<<24576, 256, 0, stream>>>(x, xb);                 // 25,165,824/4
  fill_bt1<<<4608, 256, 0, stream>>>(Bt1);                           // 1,179,648
  fill_a2<<<131072, 256, 0, stream>>>(A2);                           // 33,554,432
  transpose_f32_to_bf16<<<dim3(96, 24), 256, 0, stream>>>(W1, W1t, 768, 3072);
  transpose_f32_to_bf16<<<dim3(24, 96), 256, 0, stream>>>(W2, W2t, 3072, 768);

  // --- GEMM1: T = xb @ Bt1^T, written transpose-packed into Bt2 ---
  gemm_bt<0><<<dim3(256, 12, 1), 256, 0, stream>>>(
      xb, Bt1, 768, 768, 768, 0L, nullptr, Bt2, nullptr, nullptr, nullptr, 0);

  // --- GEMM2 (per batch): y1 = [CS|-SS] @ [Tc;Ts] + x -> d_out ---
  gemm_bt<1><<<dim3(32, 6, 8), 256, 0, stream>>>(
      A2, Bt2, 8192, 8192, 8192, 768L * 8192L, out, nullptr, x, nullptr, nullptr, 0);

  // --- LN1 -> out1 (bf16) ---
  ln_row<0><<<32768, 256, 0, stream>>>(out, g1, be1, o1b, nullptr);

  // --- GEMM3: H = gelu(out1 @ W1 + b1) ---
  gemm_bt<2><<<dim3(256, 24, 1), 256, 0, stream>>>(
      o1b, W1t, 768, 768, 768, 0L, nullptr, H, nullptr, b1, nullptr, 3072);

  // --- GEMM4: y2 = H @ W2 + b2 + out1 -> d_out ---
  gemm_bt<3><<<dim3(256, 6, 1), 256, 0, stream>>>(
      H, W2t, 3072, 3072, 3072, 0L, out, nullptr, nullptr, b2, o1b, 768);

  // --- LN2 in-place ---
  ln_row<1><<<32768, 256, 0, stream>>>(out, g2, be2, nullptr, out);
}

// Round 3
// 1006.712 us; speedup vs baseline: 1.2724x; 1.2724x over previous
//
#include <hip/hip_runtime.h>
#include <cstdint>

// FNet block on MI355X.
//   attn = Re(FFT2(x)) via bf16 MFMA matmuls + real-input quadrant symmetry:
//     GEMM1: T[r][0:512]=Tc, T[r][512:1024]=Ts   (M=32768, N=1024, K=768)
//     transpose_T: BtU[b][d][s]=Tc[s,d], BtV[b][d][s]=Ts[s,d]
//     GEMM_u: u[z][k][d] = sum_s cos(2pi k s/4096) Tc[s,d]  (M=2176,N=512,K=4096)
//     GEMM_v: v[z][k][d] = sum_s sin(2pi k s/4096) Ts[s,d]
//     combine: attn[k,d]=u-v; [k,768-d]=u+v; [4096-k,d]=u+v; [4096-k,768-d]=u-v
//              each y1 position written exactly once, fused +x residual.
//   LN1 -> out1 (bf16)
//   GEMM3: H = gelu(out1 @ W1 + b1)       (M=32768, N=3072, K=768)
//   GEMM4: y2 = H @ W2 + b2 + out1        (M=32768, N=768, K=3072)
//   LN2 in-place on d_out.
// Workspace: ~249 MiB with aliasing (u aliases dead xb; v aliases dead T;
// H aliases all dead FFT buffers).

typedef __attribute__((ext_vector_type(8))) short short8;
typedef __attribute__((ext_vector_type(4))) float f32x4;

__device__ __forceinline__ unsigned short f2b(float f) {
  union { float f; uint32_t u; } c; c.f = f;
  uint32_t u = c.u;
  u += 0x7FFFu + ((u >> 16) & 1u);   // round-to-nearest-even
  return (unsigned short)(u >> 16);
}
__device__ __forceinline__ float b2f(unsigned short h) {
  union { uint32_t u; float f; } c; c.u = ((uint32_t)h) << 16;
  return c.f;
}

// ---------------------------------------------------------------------------
// Fill / convert kernels
// ---------------------------------------------------------------------------

__global__ __launch_bounds__(256) void f32_to_bf16_vec(
    const float* __restrict__ in, unsigned short* __restrict__ out) {
  long i = (long)blockIdx.x * 256 + threadIdx.x;   // element-of-4 index
  float4 v = reinterpret_cast<const float4*>(in)[i];
  ushort4 o;
  o.x = f2b(v.x); o.y = f2b(v.y); o.z = f2b(v.z); o.w = f2b(v.w);
  reinterpret_cast<ushort4*>(out)[i] = o;
}

// Bt1: (1024 x 768). Row j<512: cos(2*pi*j*n/768); row j>=512: sin(2*pi*(j-512)*n/768).
__global__ __launch_bounds__(256) void fill_bt1(unsigned short* __restrict__ Bt1) {
  int i = blockIdx.x * 256 + threadIdx.x;          // < 1024*768
  int j = i / 768;
  int n = i - j * 768;
  int jj = j & 511;
  int m = (jj * n) % 768;
  float ang = (float)m * (6.283185307179586f / 768.0f);
  Bt1[i] = f2b((j < 512) ? cosf(ang) : sinf(ang));
}

// Au[k][s] = cos(2*pi*k*s/4096), Av[k][s] = sin(...), k=0..2175, s=0..4095.
__global__ __launch_bounds__(256) void fill_auv(
    unsigned short* __restrict__ Au, unsigned short* __restrict__ Av) {
  long i = (long)blockIdx.x * 256 + threadIdx.x;   // < 2176*4096
  int k = (int)(i >> 12);
  int s = (int)(i & 4095);
  int mm = (k * s) & 4095;
  float ang = (float)mm * (6.283185307179586f / 4096.0f);
  Au[i] = f2b(cosf(ang));
  Av[i] = f2b(sinf(ang));
}

// out[c][r] = bf16(in[r][c]); R,C multiples of 32  (for W1, W2)
__global__ __launch_bounds__(256) void transpose_f32_to_bf16(
    const float* __restrict__ in, unsigned short* __restrict__ out, int R, int C) {
  __shared__ float tile[32][33];
  const int c0 = blockIdx.x * 32;
  const int r0 = blockIdx.y * 32;
  const int tx = threadIdx.x & 31;
  const int ty = threadIdx.x >> 5;   // 0..7
#pragma unroll
  for (int i = ty; i < 32; i += 8)
    tile[i][tx] = in[(long)(r0 + i) * C + c0 + tx];
  __syncthreads();
#pragma unroll
  for (int i = ty; i < 32; i += 8)
    out[(long)(c0 + i) * R + r0 + tx] = f2b(tile[tx][i]);
}

// BtUV[(d<512?0:HALF) + (b*512 + (d&511))*4096 + s] = T[(b*4096+s)*1024 + d]
__global__ __launch_bounds__(256) void transpose_T(
    const unsigned short* __restrict__ T, unsigned short* __restrict__ BtUV) {
  __shared__ unsigned short tile[32][33];
  const int s0 = blockIdx.x * 32;
  const int d0 = blockIdx.y * 32;
  const int b  = blockIdx.z;
  const int tx = threadIdx.x & 31;
  const int ty = threadIdx.x >> 5;   // 0..7
  const unsigned short* Tb = T + ((long)b * 4096 + s0) * 1024 + d0;
#pragma unroll
  for (int i = ty; i < 32; i += 8)
    tile[i][tx] = Tb[(long)i * 1024 + tx];       // tile[s_local][d_local]
  __syncthreads();
#pragma unroll
  for (int i = ty; i < 32; i += 8) {
    const int d = d0 + i;
    const long off = (d < 512) ? 0L : 16777216L;
    BtUV[off + ((long)b * 512 + (d & 511)) * 4096 + s0 + tx] = tile[tx][i];
  }
}

// ---------------------------------------------------------------------------
// GEMM: C = A (MxK, row-major bf16) @ Bt^T (Bt is NxK row-major bf16)
// 128x128 tile, BK=32, 4 waves (2x2), 4x4 fragments of 16x16x32 MFMA.
// Epilogues (all plain linear stores):
//   0 = bf16 store, stride ldOut                      (GEMM1 -> T)
//   1 = fp32 store, z*oBatch + r*ldOut + col          (GEMM_u / GEMM_v)
//   2 = +bias, exact gelu, bf16 store                 (GEMM3 -> H)
//   3 = +bias +bf16 residual, fp32 store              (GEMM4 -> y2)
// M,N multiples of 128; K multiple of 32.
// ---------------------------------------------------------------------------

#define TILE 128
#define BKK 32

template <int EPI>
__global__ __launch_bounds__(256, 2) void gemm_bt(
    const unsigned short* __restrict__ A, const unsigned short* __restrict__ Bt,
    int K, int lda, int ldb, long bBatch, long oBatch,
    float* __restrict__ outF, unsigned short* __restrict__ outB,
    const float* __restrict__ bias, const unsigned short* __restrict__ residB,
    int ldOut) {
  __shared__ __align__(16) unsigned short As[TILE * BKK];
  __shared__ __align__(16) unsigned short Bs[TILE * BKK];
  const int tid = threadIdx.x;
  const int lane = tid & 63;
  const int wave = tid >> 6;
  const int wr = wave >> 1;        // wave row (0..1)
  const int wc = wave & 1;         // wave col (0..1)
  const int z = blockIdx.z;

  const unsigned short* Ab = A + (long)blockIdx.x * TILE * lda;
  const unsigned short* Bb = Bt + (long)z * bBatch + (long)blockIdx.y * TILE * ldb;

  const int srow = lane >> 2;            // 0..15
  const int scol = (lane & 3) << 3;      // 0,8,16,24

  f32x4 acc[4][4] = {};

  for (int k0 = 0; k0 < K; k0 += BKK) {
#pragma unroll
    for (int i = 0; i < 2; ++i) {
      const int chunk = wave * 2 + i;          // 0..7, wave-uniform
      const int row = chunk * 16 + srow;       // tile row this lane stages
      __builtin_amdgcn_global_load_lds(
          (const __attribute__((address_space(1))) void*)(Ab + (long)row * lda + k0 + scol),
          (__attribute__((address_space(3))) void*)(As + chunk * 512), 16, 0, 0);
      __builtin_amdgcn_global_load_lds(
          (const __attribute__((address_space(1))) void*)(Bb + (long)row * ldb + k0 + scol),
          (__attribute__((address_space(3))) void*)(Bs + chunk * 512), 16, 0, 0);
    }
    __syncthreads();   // drains vmcnt (global_load_lds) + lgkm

    short8 af[4], bfr[4];
#pragma unroll
    for (int m = 0; m < 4; ++m)
      af[m] = *reinterpret_cast<const short8*>(
          As + (wr * 64 + m * 16 + (lane & 15)) * BKK + ((lane >> 4) << 3));
#pragma unroll
    for (int n = 0; n < 4; ++n)
      bfr[n] = *reinterpret_cast<const short8*>(
          Bs + (wc * 64 + n * 16 + (lane & 15)) * BKK + ((lane >> 4) << 3));
#pragma unroll
    for (int m = 0; m < 4; ++m)
#pragma unroll
      for (int n = 0; n < 4; ++n)
        acc[m][n] = __builtin_amdgcn_mfma_f32_16x16x32_bf16(af[m], bfr[n], acc[m][n], 0, 0, 0);
    __syncthreads();
  }

  // Epilogue. C/D layout: col = lane&15, row = (lane>>4)*4 + reg  [m89/m91]
  const long rowBase = (long)blockIdx.x * TILE + wr * 64 + ((lane >> 4) << 2);
  const int colBase = blockIdx.y * TILE + wc * 64 + (lane & 15);
#pragma unroll
  for (int m = 0; m < 4; ++m) {
#pragma unroll
    for (int n = 0; n < 4; ++n) {
      const int col = colBase + n * 16;
#pragma unroll
      for (int i = 0; i < 4; ++i) {
        const long r = rowBase + m * 16 + i;
        float v = acc[m][n][i];
        if constexpr (EPI == 0) {
          outB[r * (long)ldOut + col] = f2b(v);
        } else if constexpr (EPI == 1) {
          outF[(long)z * oBatch + r * (long)ldOut + col] = v;
        } else if constexpr (EPI == 2) {
          float t = v + bias[col];
          float g = 0.5f * t * (1.0f + erff(t * 0.7071067811865476f));
          outB[r * (long)ldOut + col] = f2b(g);
        } else {
          const long idx = r * (long)ldOut + col;
          outF[idx] = v + bias[col] + b2f(residB[idx]);
        }
      }
    }
  }
}

// ---------------------------------------------------------------------------
// Quadrant combine: y1 = attn + x, each output written exactly once.
//   attn[k,d]        = u[k,d] - v[k,d]        (k<=2048, d<=384)
//   attn[k,768-d]    = u[k,d] + v[k,d]
//   attn[4096-k,d]   = u[k,d] + v[k,d]
//   attn[4096-k,768-d] = u[k,d] - v[k,d]
// ---------------------------------------------------------------------------
__global__ __launch_bounds__(256) void combine_quadrants(
    const float* __restrict__ u, const float* __restrict__ v,
    const float* __restrict__ x, float* __restrict__ y) {
  const int k = blockIdx.x;            // 0..2048
  const int z = blockIdx.y;            // 0..7
  const long ub = ((long)z * 2176 + k) * 512;
  const long base = (long)z * 4096 * 768;
  const long rowA = base + (long)k * 768;
  const long rowB = base + (long)(4096 - k) * 768;
  const bool doRowB = (k != 0) && (k != 2048);
  for (int d = threadIdx.x; d <= 384; d += 256) {
    const float uu = u[ub + d];
    const float vv = v[ub + d];
    const float a1 = uu - vv;
    const float a2 = uu + vv;
    const int dd = 768 - d;
    const bool doColB = (d != 0) && (d != 384);
    y[rowA + d] = a1 + x[rowA + d];
    if (doColB) y[rowA + dd] = a2 + x[rowA + dd];
    if (doRowB) {
      y[rowB + d] = a2 + x[rowB + d];
      if (doColB) y[rowB + dd] = a1 + x[rowB + dd];
    }
  }
}

// ---------------------------------------------------------------------------
// Row LayerNorm over D=768. One 256-thread block per row, 3 elems/thread.
// MODE 0: write bf16 (out1). MODE 1: write fp32 (in-place final output).
// ---------------------------------------------------------------------------
template <int MODE>
__global__ __launch_bounds__(256) void ln_row(
    const float* __restrict__ in, const float* __restrict__ gamma,
    const float* __restrict__ beta, unsigned short* __restrict__ outB,
    float* __restrict__ outF) {
  const long row = blockIdx.x;
  const float* p = in + row * 768;
  const int t = threadIdx.x;
  const float v0 = p[t], v1 = p[t + 256], v2 = p[t + 512];
  float s = v0 + v1 + v2;
  float q = v0 * v0 + v1 * v1 + v2 * v2;
#pragma unroll
  for (int off = 32; off > 0; off >>= 1) {
    s += __shfl_down(s, off, 64);
    q += __shfl_down(q, off, 64);
  }
  __shared__ float ss[4], sq[4];
  if ((t & 63) == 0) { ss[t >> 6] = s; sq[t >> 6] = q; }
  __syncthreads();
  const float S = ss[0] + ss[1] + ss[2] + ss[3];
  const float Q = sq[0] + sq[1] + sq[2] + sq[3];
  const float mu = S * (1.0f / 768.0f);
  const float var = Q * (1.0f / 768.0f) - mu * mu;
  const float rs = rsqrtf(var + 1e-6f);
  const float o0 = (v0 - mu) * rs * gamma[t] + beta[t];
  const float o1 = (v1 - mu) * rs * gamma[t + 256] + beta[t + 256];
  const float o2 = (v2 - mu) * rs * gamma[t + 512] + beta[t + 512];
  if constexpr (MODE == 0) {
    outB[row * 768 + t] = f2b(o0);
    outB[row * 768 + t + 256] = f2b(o1);
    outB[row * 768 + t + 512] = f2b(o2);
  } else {
    outF[row * 768 + t] = o0;
    outF[row * 768 + t + 256] = o1;
    outF[row * 768 + t + 512] = o2;
  }
}

// ---------------------------------------------------------------------------

extern "C" void kernel_launch(void* const* d_in, const int* in_sizes, int n_in,
                              void* d_out, int out_size, void* d_ws, size_t ws_size,
                              hipStream_t stream) {
  const float* x   = (const float*)d_in[0];   // (8,4096,768)
  const float* W1  = (const float*)d_in[1];   // (768,3072)
  const float* b1  = (const float*)d_in[2];   // (3072)
  const float* W2  = (const float*)d_in[3];   // (3072,768)
  const float* b2  = (const float*)d_in[4];   // (768)
  const float* g1  = (const float*)d_in[5];
  const float* be1 = (const float*)d_in[6];
  const float* g2  = (const float*)d_in[7];
  const float* be2 = (const float*)d_in[8];
  float* out = (float*)d_out;                 // fp32, also y1/y2 scratch

  char* ws = (char*)d_ws;
  unsigned short* xb   = (unsigned short*)(ws + 0L);           //  50,331,648
  unsigned short* Bt1  = (unsigned short*)(ws + 50331648L);    //   1,572,864
  unsigned short* Au   = (unsigned short*)(ws + 51904512L);    //  17,825,792
  unsigned short* Av   = (unsigned short*)(ws + 69730304L);    //  17,825,792
  unsigned short* T    = (unsigned short*)(ws + 87556096L);    //  67,108,864 -> ends 154,664,960
  unsigned short* BtUV = (unsigned short*)(ws + 154664960L);   //  67,108,864 -> ends 221,773,824
  float*          u    = (float*)        (ws + 0L);            //  35,651,584 (aliases xb; xb dead after GEMM1)
  float*          v    = (float*)        (ws + 87556096L);     //  35,651,584 (aliases T; T dead after transpose_T)
  unsigned short* H    = (unsigned short*)(ws + 0L);           // 201,326,592 (aliases all FFT buffers, dead by GEMM3)
  unsigned short* o1b  = (unsigned short*)(ws + 201326592L);   //  50,331,648 (overlaps BtUV tail, dead by LN1)
  unsigned short* W1t  = (unsigned short*)(ws + 251658240L);   //   4,718,592
  unsigned short* W2t  = (unsigned short*)(ws + 256376832L);   //   4,718,592
  // total ws needed: 261,095,424 bytes (~249 MiB)

  // --- prep ---
  f32_to_bf16_vec<<<24576, 256, 0, stream>>>(x, xb);
  fill_bt1<<<3072, 256, 0, stream>>>(Bt1);
  fill_auv<<<34816, 256, 0, stream>>>(Au, Av);
  transpose_f32_to_bf16<<<dim3(96, 24), 256, 0, stream>>>(W1, W1t, 768, 3072);
  transpose_f32_to_bf16<<<dim3(24, 96), 256, 0, stream>>>(W2, W2t, 3072, 768);

  // --- GEMM1: T = xb @ Bt1^T (row-major, ld 1024) ---
  gemm_bt<0><<<dim3(256, 8, 1), 256, 0, stream>>>(
      xb, Bt1, 768, 768, 768, 0L, 0L, nullptr, T, nullptr, nullptr, 1024);

  // --- transpose T -> BtU/BtV ([b][d][s]) ---
  transpose_T<<<dim3(128, 32, 8), 256, 0, stream>>>(T, BtUV);

  // --- GEMM_u (per batch): u = C_S @ Tc ---
  gemm_bt<1><<<dim3(17, 4, 8), 256, 0, stream>>>(
      Au, BtUV, 4096, 4096, 4096, 512L * 4096L, 2176L * 512L,
      u, nullptr, nullptr, nullptr, 512);

  // --- GEMM_v (per batch): v = S_S @ Ts ---
  gemm_bt<1><<<dim3(17, 4, 8), 256, 0, stream>>>(
      Av, BtUV + 16777216L, 4096, 4096, 4096, 512L * 4096L, 2176L * 512L,
      v, nullptr, nullptr, nullptr, 512);

  // --- combine quadrants + x residual -> y1 (d_out) ---
  combine_quadrants<<<dim3(2049, 8), 256, 0, stream>>>(u, v, x, out);

  // --- LN1 -> out1 (bf16) ---
  ln_row<0><<<32768, 256, 0, stream>>>(out, g1, be1, o1b, nullptr);

  // --- GEMM3: H = gelu(out1 @ W1 + b1) ---
  gemm_bt<2><<<dim3(256, 24, 1), 256, 0, stream>>>(
      o1b, W1t, 768, 768, 768, 0L, 0L, nullptr, H, b1, nullptr, 3072);

  // --- GEMM4: y2 = H @ W2 + b2 + out1 -> d_out ---
  gemm_bt<3><<<dim3(256, 6, 1), 256, 0, stream>>>(
      H, W2t, 3072, 3072, 3072, 0L, 0L, out, nullptr, b2, o1b, 768);

  // --- LN2 in-place ---
  ln_row<1><<<32768, 256, 0, stream>>>(out, g2, be2, nullptr, out);
}